// Round 1
// baseline (926.517 us; speedup 1.0000x reference)
//
#include <hip/hip_runtime.h>
#include <cstddef>

#define FG 6
#define L 1024
#define NB 768
#define MN 8
#define H 16
#define HD 64
#define ADIM 1024
#define EMBED 1024
#define STAGES 4
#define BQ 2            /* B/FG = 12/6 */
#define SCALE 0.125f

#define QBUF_SZ (BQ*NB*ADIM)            /* 1,572,864 floats */
#define KVBUF_SZ (BQ*NB*MN*2*ADIM)      /* 25,165,824 floats */

__device__ __forceinline__ int clampi(int v, int lo, int hi) {
  return v < lo ? lo : (v > hi ? hi : v);
}

template<int MODE>
__device__ __forceinline__ long src_row(int r, const int* __restrict__ f_ids,
                                        const int* __restrict__ t_ids) {
  if (MODE == 2) return r;
  int bi, idx;
  if (MODE == 0) { bi = r / NB; idx = r - bi * NB; }
  else           { bi = r / (NB*MN); idx = r - bi * (NB*MN); }
  int f = clampi(f_ids[idx], 0, FG - 1);
  int q = clampi(t_ids[idx], 0, L - 1);
  return (long)(bi * FG + f) * L + q;
}

// MODE 0: Q-GEMM   A=x gathered rows, B=qkv_w cols [0,1024),   C=qbuf  (ldc 1024)
// MODE 1: KV-GEMM  A=x gathered rows, B=qkv_w cols [1024,3072),C=kvbuf (ldc 2048)
// MODE 2: OUT-GEMM A=qbuf rows,       B=out_w,                 C=d_out scatter+bias+valid
template<int MODE>
__global__ __launch_bounds__(256)
void sgemm_kernel(const float* __restrict__ A, const float* __restrict__ Bm,
                  float* __restrict__ C,
                  const int* __restrict__ f_ids, const int* __restrict__ t_ids,
                  const float* __restrict__ bias)
{
  constexpr int LDB   = (MODE == 2) ? 1024 : 3072;
  constexpr int BCOL0 = (MODE == 1) ? 1024 : 0;
  constexpr int LDC   = (MODE == 1) ? 2048 : 1024;

  __shared__ float As[16][128];
  __shared__ float Bs[16][128];

  const int tid  = threadIdx.x;
  const int row0 = blockIdx.y * 128;
  const int col0 = blockIdx.x * 128;

  // A staging: thread loads rows (row0+ra) and (row0+64+ra), k-chunk kc..kc+3
  const int ra = tid & 63;
  const int kc = (tid >> 6) << 2;
  const long s1 = src_row<MODE>(row0 + ra,      f_ids, t_ids);
  const long s2 = src_row<MODE>(row0 + 64 + ra, f_ids, t_ids);
  const float* ap1 = A + s1 * 1024 + kc;
  const float* ap2 = A + s2 * 1024 + kc;

  // B staging: thread loads rows bk and bk+8 of the 16xK-tile, 4 cols at bc
  const int bk = tid >> 5;          // 0..7
  const int bc = (tid & 31) << 2;   // 0..124
  const float* bp = Bm + (size_t)bk * LDB + BCOL0 + col0 + bc;

  const int tcol = tid & 15, trow = tid >> 4;

  float acc[8][8];
  #pragma unroll
  for (int i = 0; i < 8; ++i)
    #pragma unroll
    for (int j = 0; j < 8; ++j) acc[i][j] = 0.f;

  for (int kt = 0; kt < 64; ++kt) {
    const float4 a0 = *(const float4*)(ap1 + kt * 16);
    const float4 a1 = *(const float4*)(ap2 + kt * 16);
    const float4 b0 = *(const float4*)(bp + (size_t)(kt * 16) * LDB);
    const float4 b1 = *(const float4*)(bp + (size_t)(kt * 16 + 8) * LDB);

    __syncthreads();
    As[kc + 0][ra] = a0.x; As[kc + 1][ra] = a0.y;
    As[kc + 2][ra] = a0.z; As[kc + 3][ra] = a0.w;
    As[kc + 0][ra + 64] = a1.x; As[kc + 1][ra + 64] = a1.y;
    As[kc + 2][ra + 64] = a1.z; As[kc + 3][ra + 64] = a1.w;
    *(float4*)&Bs[bk][bc]     = b0;
    *(float4*)&Bs[bk + 8][bc] = b1;
    __syncthreads();

    #pragma unroll
    for (int k = 0; k < 16; ++k) {
      float a[8], b[8];
      *(float4*)&a[0] = *(const float4*)&As[k][trow * 8];
      *(float4*)&a[4] = *(const float4*)&As[k][trow * 8 + 4];
      *(float4*)&b[0] = *(const float4*)&Bs[k][tcol * 8];
      *(float4*)&b[4] = *(const float4*)&Bs[k][tcol * 8 + 4];
      #pragma unroll
      for (int i = 0; i < 8; ++i)
        #pragma unroll
        for (int j = 0; j < 8; ++j)
          acc[i][j] = fmaf(a[i], b[j], acc[i][j]);
    }
  }

  if (MODE != 2) {
    #pragma unroll
    for (int i = 0; i < 8; ++i) {
      int row = row0 + trow * 8 + i;
      float* cp = C + (size_t)row * LDC + col0 + tcol * 8;
      float4 v0 = { acc[i][0], acc[i][1], acc[i][2], acc[i][3] };
      float4 v1 = { acc[i][4], acc[i][5], acc[i][6], acc[i][7] };
      *(float4*)cp       = v0;
      *(float4*)(cp + 4) = v1;
    }
  } else {
    float bb[8];
    *(float4*)&bb[0] = *(const float4*)(bias + col0 + tcol * 8);
    *(float4*)&bb[4] = *(const float4*)(bias + col0 + tcol * 8 + 4);
    #pragma unroll
    for (int i = 0; i < 8; ++i) {
      int r  = row0 + trow * 8 + i;
      int bi = r / NB, n = r - bi * NB;
      int bf = f_ids[n], bt = t_ids[n];
      int qf = clampi(bf, 0, FG - 1), qi = clampi(bt, 0, L - 1);
      float valid = (bf == qf && bt == qi) ? 1.0f : 0.0f;
      size_t base = ((size_t)(bi * FG + qf) * L + qi) * 1024 + col0 + tcol * 8;
      float4 v0 = { (acc[i][0] + bb[0]) * valid, (acc[i][1] + bb[1]) * valid,
                    (acc[i][2] + bb[2]) * valid, (acc[i][3] + bb[3]) * valid };
      float4 v1 = { (acc[i][4] + bb[4]) * valid, (acc[i][5] + bb[5]) * valid,
                    (acc[i][6] + bb[6]) * valid, (acc[i][7] + bb[7]) * valid };
      *(float4*)(C + base)     = v0;
      *(float4*)(C + base + 4) = v1;
    }
  }
}

// One wave per (bi, n, h). lane = head-dim. Fuses: q/k/v ray rotation,
// QK^T scores, softmax over 8 neighbors, PV, inverse rotation of output.
// Writes the pre-projection output back into qbuf (same location as q).
__global__ __launch_bounds__(256)
void attn_kernel(const float* __restrict__ dray,
                 const int* __restrict__ bfid, const int* __restrict__ blid,
                 const int* __restrict__ bsid,
                 const int* __restrict__ nfid, const int* __restrict__ ntid,
                 const int* __restrict__ nlid, const int* __restrict__ nsid,
                 const int* __restrict__ nmask,
                 float* __restrict__ qbuf, const float* __restrict__ kvbuf)
{
  const int lane = threadIdx.x & 63;
  const int gw   = blockIdx.x * 4 + (threadIdx.x >> 6);
  const int h    = gw & (H - 1);
  const int bn   = gw >> 4;          // bi*NB + n
  const int n    = bn % NB;

  // d_q (broadcast loads)
  int st = clampi(bsid[n], 0, STAGES - 1);
  int f  = clampi(bfid[n], 0, FG - 1);
  int lc = clampi(blid[n], 0, L - 1);
  const float* dqp = dray + ((size_t)(st * FG + f) * L + lc) * 9;
  float dq[9];
  #pragma unroll
  for (int t = 0; t < 9; ++t) dq[t] = dqp[t];

  float* qp = qbuf + (size_t)bn * ADIM + h * HD;
  const float qraw = qp[lane];
  const int rr = lane & 15;

  // rotate q: first 48 dims as (3,16), rest pass-through
  {
  }
  float x0 = __shfl(qraw, rr), x1 = __shfl(qraw, 16 + rr), x2 = __shfl(qraw, 32 + rr);
  float q0 = dq[0]*x0 + dq[1]*x1 + dq[2]*x2;
  float q1 = dq[3]*x0 + dq[4]*x1 + dq[5]*x2;
  float q2 = dq[6]*x0 + dq[7]*x1 + dq[8]*x2;
  float qd = lane < 16 ? q0 : lane < 32 ? q1 : lane < 48 ? q2 : qraw;

  const float* kvb = kvbuf + (size_t)bn * MN * 2048 + h * HD;
  float s[MN], vd[MN];
  #pragma unroll
  for (int m = 0; m < MN; ++m) {
    const int idx = n * MN + m;
    int nst = clampi(nsid[idx], 0, STAGES - 1);
    int nfc = clampi(nfid[idx], 0, FG - 1);
    int nlc = clampi(nlid[idx], 0, L - 1);
    const float* dkp = dray + ((size_t)(nst * FG + nfc) * L + nlc) * 9;
    float dk[9];
    #pragma unroll
    for (int t = 0; t < 9; ++t) dk[t] = dkp[t];

    float kraw = kvb[(size_t)m * 2048 + lane];
    float k0 = __shfl(kraw, rr), k1 = __shfl(kraw, 16 + rr), k2 = __shfl(kraw, 32 + rr);
    float kr0 = dk[0]*k0 + dk[1]*k1 + dk[2]*k2;
    float kr1 = dk[3]*k0 + dk[4]*k1 + dk[5]*k2;
    float kr2 = dk[6]*k0 + dk[7]*k1 + dk[8]*k2;
    float kd = lane < 16 ? kr0 : lane < 32 ? kr1 : lane < 48 ? kr2 : kraw;

    float p = qd * kd;
    #pragma unroll
    for (int off = 32; off; off >>= 1) p += __shfl_xor(p, off);
    s[m] = p;

    float vraw = kvb[(size_t)m * 2048 + 1024 + lane];
    float v0 = __shfl(vraw, rr), v1 = __shfl(vraw, 16 + rr), v2 = __shfl(vraw, 32 + rr);
    float vr0 = dk[0]*v0 + dk[1]*v1 + dk[2]*v2;
    float vr1 = dk[3]*v0 + dk[4]*v1 + dk[5]*v2;
    float vr2 = dk[6]*v0 + dk[7]*v1 + dk[8]*v2;
    vd[m] = lane < 16 ? vr0 : lane < 32 ? vr1 : lane < 48 ? vr2 : vraw;
  }

  // mask + softmax over m
  float mx = -INFINITY;
  #pragma unroll
  for (int m = 0; m < MN; ++m) {
    const int idx = n * MN + m;
    int nf = nfid[idx], nt = ntid[idx];
    bool ok = (nmask[idx] != 0) && nf >= 0 && nf < FG && nt >= 0 && nt < L;
    s[m] = ok ? s[m] * SCALE : -INFINITY;
    mx = fmaxf(mx, s[m]);
  }
  float den = 0.f;
  #pragma unroll
  for (int m = 0; m < MN; ++m) { s[m] = expf(s[m] - mx); den += s[m]; }
  float inv = 1.0f / den;

  float od = 0.f;
  #pragma unroll
  for (int m = 0; m < MN; ++m) od += s[m] * vd[m];
  od *= inv;

  // inverse rotation (d_q transposed)
  float y0 = __shfl(od, rr), y1 = __shfl(od, 16 + rr), y2 = __shfl(od, 32 + rr);
  float t0 = dq[0]*y0 + dq[3]*y1 + dq[6]*y2;
  float t1 = dq[1]*y0 + dq[4]*y1 + dq[7]*y2;
  float t2 = dq[2]*y0 + dq[5]*y1 + dq[8]*y2;
  float outd = lane < 16 ? t0 : lane < 32 ? t1 : lane < 48 ? t2 : od;

  qp[lane] = outd;
}

extern "C" void kernel_launch(void* const* d_in, const int* in_sizes, int n_in,
                              void* d_out, int out_size, void* d_ws, size_t ws_size,
                              hipStream_t stream) {
  const float* x     = (const float*)d_in[0];
  const float* qkv_w = (const float*)d_in[1];
  const float* out_w = (const float*)d_in[2];
  const float* out_b = (const float*)d_in[3];
  const float* dray  = (const float*)d_in[4];
  const int* bfid  = (const int*)d_in[5];
  const int* btid  = (const int*)d_in[6];
  const int* blid  = (const int*)d_in[7];
  const int* bsid  = (const int*)d_in[8];
  const int* nfid  = (const int*)d_in[9];
  const int* ntid  = (const int*)d_in[10];
  const int* nlid  = (const int*)d_in[11];
  const int* nsid  = (const int*)d_in[12];
  const int* nmask = (const int*)d_in[13];
  // d_in[14] = face_group (compile-time FG)

  float* qbuf  = (float*)d_ws;
  float* kvbuf = qbuf + QBUF_SZ;

  // zero the full output (scatter only touches NB rows per (bi, face-plane))
  hipMemsetAsync(d_out, 0, (size_t)out_size * sizeof(float), stream);

  // Q projection: (1536 x 1024) = gather(x) @ qkv_w[:, :1024]
  sgemm_kernel<0><<<dim3(8, 12), 256, 0, stream>>>(x, qkv_w, qbuf, bfid, btid, out_b);
  // KV projection: (12288 x 2048) = gather(x) @ qkv_w[:, 1024:]
  sgemm_kernel<1><<<dim3(16, 96), 256, 0, stream>>>(x, qkv_w, kvbuf, nfid, ntid, out_b);
  // fused rotations + attention (overwrites qbuf with pre-projection output)
  attn_kernel<<<6144, 256, 0, stream>>>(dray, bfid, blid, bsid,
                                        nfid, ntid, nlid, nsid, nmask,
                                        qbuf, kvbuf);
  // output projection + bias + valid mask + scatter
  sgemm_kernel<2><<<dim3(8, 12), 256, 0, stream>>>(qbuf, out_w, (float*)d_out,
                                                   bfid, btid, out_b);
}

// Round 2
// 183.445 us; speedup vs baseline: 5.0506x; 5.0506x over previous
//
#include <hip/hip_runtime.h>
#include <hip/hip_bf16.h>
#include <cstddef>

#define FG 6
#define L 1024
#define NB 768
#define MN 8
#define H 16
#define HD 64
#define ADIM 1024
#define STAGES 4
#define SCALE 0.125f

typedef __attribute__((ext_vector_type(8))) short bf16x8;
typedef __attribute__((ext_vector_type(4))) float f32x4;
typedef __attribute__((address_space(3))) short lds_short_t;
typedef const __attribute__((address_space(1))) short g_short_t;

__device__ __forceinline__ int clampi(int v, int lo, int hi) {
  return v < lo ? lo : (v > hi ? hi : v);
}

__device__ __forceinline__ short f2bf(float f) {
  __hip_bfloat16 h = __float2bfloat16(f);
  return *reinterpret_cast<short*>(&h);
}

__device__ __forceinline__ void gload16(const short* g, short* l) {
  __builtin_amdgcn_global_load_lds((g_short_t*)g, (lds_short_t*)l, 16, 0, 0);
}

// fp32 -> bf16 bulk convert (8 elems/thread)
__global__ __launch_bounds__(256)
void conv_bf16(const float* __restrict__ in, short* __restrict__ out) {
  size_t i = ((size_t)blockIdx.x * 256 + threadIdx.x) * 8;
  float4 a = *(const float4*)(in + i);
  float4 b = *(const float4*)(in + i + 4);
  bf16x8 v;
  v[0] = f2bf(a.x); v[1] = f2bf(a.y); v[2] = f2bf(a.z); v[3] = f2bf(a.w);
  v[4] = f2bf(b.x); v[5] = f2bf(b.y); v[6] = f2bf(b.z); v[7] = f2bf(b.w);
  *(bf16x8*)(out + i) = v;
}

// in fp32 [K][N] -> out bf16 [N][K]  (B^T layout for the GEMM)
__global__ __launch_bounds__(256)
void transpose_conv(const float* __restrict__ in, short* __restrict__ out,
                    int K, int N) {
  __shared__ float tile[32][33];
  const int n0 = blockIdx.x * 32, k0 = blockIdx.y * 32;
  const int tx = threadIdx.x & 31, ty = threadIdx.x >> 5;
  #pragma unroll
  for (int i = 0; i < 4; ++i)
    tile[ty + i * 8][tx] = in[(size_t)(k0 + ty + i * 8) * N + n0 + tx];
  __syncthreads();
  #pragma unroll
  for (int i = 0; i < 4; ++i)
    out[(size_t)(n0 + ty + i * 8) * K + k0 + tx] =
        f2bf(tile[tx][ty + i * 8]);
}

// MODE 0: Q   A=xb gathered (bfid,btid), B=qwT[0:1024),    C=qbuf fp32 ldc1024
// MODE 1: KV  A=xb gathered (nfid,ntid), B=qwT[1024:3072), C=kvbuf bf16 ldc2048
// MODE 2: OUT A=obuf direct,             B=owT,            C=d_out fp32 scatter
// 128x128 tile, BK=64, 4 waves 2x2 (64x64 each), mfma_f32_16x16x32_bf16.
// LDS tiles XOR-swizzled (slot ^= row&7); the swizzle is applied to the
// GLOBAL source address at staging (global_load_lds dest must be linear).
template<int MODE>
__global__ __launch_bounds__(256)
void mfma_gemm(const short* __restrict__ A, const short* __restrict__ B,
               void* __restrict__ Cv,
               const int* __restrict__ f_ids, const int* __restrict__ t_ids,
               const float* __restrict__ bias)
{
  constexpr int KT    = 16;                    // 1024 / 64
  constexpr int BCOL0 = (MODE == 1) ? 1024 : 0;

  __shared__ __align__(16) short As[8192];     // 128 rows x 64 bf16 (swizzled)
  __shared__ __align__(16) short Bs[8192];

  const int tid  = threadIdx.x;
  const int w    = tid >> 6, lane = tid & 63;
  const int row0 = blockIdx.y * 128, col0 = blockIdx.x * 128;

  // ---- staging address precompute (4 x 1KB chunks per wave per tile) ----
  size_t aoff[4], boff[4];
  short *adst[4], *bdst[4];
  #pragma unroll
  for (int c = 0; c < 4; ++c) {
    const int d = (w * 4 + c) * 64 + lane;     // 16B-slot index in tile
    const int r = d >> 3;                      // tile row 0..127
    const int ssrc = (d & 7) ^ (r & 7);        // inverse-swizzled source slot
    long gr;
    if (MODE == 2) {
      gr = row0 + r;
    } else {
      const int rr = row0 + r;
      int bi, idx;
      if (MODE == 0) { bi = rr >= NB;          idx = rr - bi * NB; }
      else           { bi = rr >= NB * MN;     idx = rr - bi * NB * MN; }
      const int f = clampi(f_ids[idx], 0, FG - 1);
      const int q = clampi(t_ids[idx], 0, L - 1);
      gr = (long)(bi * FG + f) * L + q;
    }
    aoff[c] = (size_t)gr * 1024 + ssrc * 8;
    boff[c] = (size_t)(BCOL0 + col0 + r) * 1024 + ssrc * 8;
    adst[c] = As + (w * 4 + c) * 512;
    bdst[c] = Bs + (w * 4 + c) * 512;
  }

  // ---- fragment read offsets ----
  const int lr = lane & 15, lq = lane >> 4;
  const int wrow = (w >> 1) * 64, wcol = (w & 1) * 64;
  const int sA = lr & 7;                       // swizzle key (row&7)
  const char* As8 = (const char*)As;
  const char* Bs8 = (const char*)Bs;
  const int abase = (wrow + lr) * 128;
  const int bbase = (wcol + lr) * 128;

  f32x4 acc[4][4];
  #pragma unroll
  for (int m = 0; m < 4; ++m)
    #pragma unroll
    for (int n = 0; n < 4; ++n) acc[m][n] = (f32x4){0.f, 0.f, 0.f, 0.f};

  for (int kt = 0; kt < KT; ++kt) {
    #pragma unroll
    for (int c = 0; c < 4; ++c) {
      gload16(A + aoff[c] + kt * 64, adst[c]);
      gload16(B + boff[c] + kt * 64, bdst[c]);
    }
    __syncthreads();                           // drains vmcnt before barrier
    #pragma unroll
    for (int kk = 0; kk < 2; ++kk) {
      const int so = ((kk * 4 + lq) ^ sA) << 4;
      bf16x8 av[4], bv[4];
      #pragma unroll
      for (int m = 0; m < 4; ++m)
        av[m] = *(const bf16x8*)(As8 + abase + m * 2048 + so);
      #pragma unroll
      for (int n = 0; n < 4; ++n)
        bv[n] = *(const bf16x8*)(Bs8 + bbase + n * 2048 + so);
      #pragma unroll
      for (int m = 0; m < 4; ++m)
        #pragma unroll
        for (int n = 0; n < 4; ++n)
          acc[m][n] = __builtin_amdgcn_mfma_f32_16x16x32_bf16(
              av[m], bv[n], acc[m][n], 0, 0, 0);
    }
    __syncthreads();                           // reads done before next stage
  }

  // ---- epilogue: C/D layout col=lane&15, row=(lane>>4)*4+reg ----
  if (MODE == 0) {
    float* C = (float*)Cv;
    #pragma unroll
    for (int m = 0; m < 4; ++m)
      #pragma unroll
      for (int j = 0; j < 4; ++j) {
        const int r = row0 + wrow + m * 16 + lq * 4 + j;
        #pragma unroll
        for (int n = 0; n < 4; ++n)
          C[(size_t)r * 1024 + col0 + wcol + n * 16 + lr] = acc[m][n][j];
      }
  } else if (MODE == 1) {
    short* C = (short*)Cv;
    #pragma unroll
    for (int m = 0; m < 4; ++m)
      #pragma unroll
      for (int j = 0; j < 4; ++j) {
        const int r = row0 + wrow + m * 16 + lq * 4 + j;
        #pragma unroll
        for (int n = 0; n < 4; ++n)
          C[(size_t)r * 2048 + col0 + wcol + n * 16 + lr] = f2bf(acc[m][n][j]);
      }
  } else {
    float* C = (float*)Cv;
    float bb[4];
    #pragma unroll
    for (int n = 0; n < 4; ++n) bb[n] = bias[col0 + wcol + n * 16 + lr];
    #pragma unroll
    for (int m = 0; m < 4; ++m)
      #pragma unroll
      for (int j = 0; j < 4; ++j) {
        const int r  = row0 + wrow + m * 16 + lq * 4 + j;
        const int bi = r >= NB;
        const int nn = r - bi * NB;
        const int bf = f_ids[nn], bt = t_ids[nn];
        const int qf = clampi(bf, 0, FG - 1), qi = clampi(bt, 0, L - 1);
        const bool valid = (bf == qf) && (bt == qi);
        const size_t obase = ((size_t)(bi * FG + qf) * L + qi) * 1024;
        #pragma unroll
        for (int n = 0; n < 4; ++n) {
          const int col = col0 + wcol + n * 16 + lr;
          C[obase + col] = valid ? (acc[m][n][j] + bb[n]) : 0.f;
        }
      }
  }
}

// One wave per (bi, n, h). Fuses q/k/v ray rotation, scores, softmax, PV,
// inverse rotation. q fp32 in, kv bf16 in, out bf16 (feeds OUT-GEMM).
__global__ __launch_bounds__(256)
void attn_kernel(const float* __restrict__ dray,
                 const int* __restrict__ bfid, const int* __restrict__ blid,
                 const int* __restrict__ bsid,
                 const int* __restrict__ nfid, const int* __restrict__ ntid,
                 const int* __restrict__ nlid, const int* __restrict__ nsid,
                 const int* __restrict__ nmask,
                 const float* __restrict__ qbuf,
                 const __hip_bfloat16* __restrict__ kvbuf,
                 __hip_bfloat16* __restrict__ obuf)
{
  const int lane = threadIdx.x & 63;
  const int gw   = blockIdx.x * 4 + (threadIdx.x >> 6);
  const int h    = gw & (H - 1);
  const int bn   = gw >> 4;          // bi*NB + n
  const int n    = bn % NB;

  int st = clampi(bsid[n], 0, STAGES - 1);
  int f  = clampi(bfid[n], 0, FG - 1);
  int lc = clampi(blid[n], 0, L - 1);
  const float* dqp = dray + ((size_t)(st * FG + f) * L + lc) * 9;
  float dq[9];
  #pragma unroll
  for (int t = 0; t < 9; ++t) dq[t] = dqp[t];

  const float qraw = qbuf[(size_t)bn * ADIM + h * HD + lane];
  const int rr = lane & 15;

  float x0 = __shfl(qraw, rr), x1 = __shfl(qraw, 16 + rr), x2 = __shfl(qraw, 32 + rr);
  float q0 = dq[0]*x0 + dq[1]*x1 + dq[2]*x2;
  float q1 = dq[3]*x0 + dq[4]*x1 + dq[5]*x2;
  float q2 = dq[6]*x0 + dq[7]*x1 + dq[8]*x2;
  float qd = lane < 16 ? q0 : lane < 32 ? q1 : lane < 48 ? q2 : qraw;

  const __hip_bfloat16* kvb = kvbuf + (size_t)bn * MN * 2048 + h * HD;
  float s[MN], vd[MN];
  #pragma unroll
  for (int m = 0; m < MN; ++m) {
    const int idx = n * MN + m;
    int nst = clampi(nsid[idx], 0, STAGES - 1);
    int nfc = clampi(nfid[idx], 0, FG - 1);
    int nlc = clampi(nlid[idx], 0, L - 1);
    const float* dkp = dray + ((size_t)(nst * FG + nfc) * L + nlc) * 9;
    float dk[9];
    #pragma unroll
    for (int t = 0; t < 9; ++t) dk[t] = dkp[t];

    float kraw = __bfloat162float(kvb[(size_t)m * 2048 + lane]);
    float k0 = __shfl(kraw, rr), k1 = __shfl(kraw, 16 + rr), k2 = __shfl(kraw, 32 + rr);
    float kr0 = dk[0]*k0 + dk[1]*k1 + dk[2]*k2;
    float kr1 = dk[3]*k0 + dk[4]*k1 + dk[5]*k2;
    float kr2 = dk[6]*k0 + dk[7]*k1 + dk[8]*k2;
    float kd = lane < 16 ? kr0 : lane < 32 ? kr1 : lane < 48 ? kr2 : kraw;

    float p = qd * kd;
    #pragma unroll
    for (int off = 32; off; off >>= 1) p += __shfl_xor(p, off);
    s[m] = p;

    float vraw = __bfloat162float(kvb[(size_t)m * 2048 + 1024 + lane]);
    float v0 = __shfl(vraw, rr), v1 = __shfl(vraw, 16 + rr), v2 = __shfl(vraw, 32 + rr);
    float vr0 = dk[0]*v0 + dk[1]*v1 + dk[2]*v2;
    float vr1 = dk[3]*v0 + dk[4]*v1 + dk[5]*v2;
    float vr2 = dk[6]*v0 + dk[7]*v1 + dk[8]*v2;
    vd[m] = lane < 16 ? vr0 : lane < 32 ? vr1 : lane < 48 ? vr2 : vraw;
  }

  float mx = -INFINITY;
  #pragma unroll
  for (int m = 0; m < MN; ++m) {
    const int idx = n * MN + m;
    int nf = nfid[idx], nt = ntid[idx];
    bool ok = (nmask[idx] != 0) && nf >= 0 && nf < FG && nt >= 0 && nt < L;
    s[m] = ok ? s[m] * SCALE : -INFINITY;
    mx = fmaxf(mx, s[m]);
  }
  float den = 0.f;
  #pragma unroll
  for (int m = 0; m < MN; ++m) { s[m] = expf(s[m] - mx); den += s[m]; }
  float inv = 1.0f / den;

  float od = 0.f;
  #pragma unroll
  for (int m = 0; m < MN; ++m) od += s[m] * vd[m];
  od *= inv;

  float y0 = __shfl(od, rr), y1 = __shfl(od, 16 + rr), y2 = __shfl(od, 32 + rr);
  float t0 = dq[0]*y0 + dq[3]*y1 + dq[6]*y2;
  float t1 = dq[1]*y0 + dq[4]*y1 + dq[7]*y2;
  float t2 = dq[2]*y0 + dq[5]*y1 + dq[8]*y2;
  float outd = lane < 16 ? t0 : lane < 32 ? t1 : lane < 48 ? t2 : od;

  obuf[(size_t)bn * ADIM + h * HD + lane] = __float2bfloat16(outd);
}

extern "C" void kernel_launch(void* const* d_in, const int* in_sizes, int n_in,
                              void* d_out, int out_size, void* d_ws, size_t ws_size,
                              hipStream_t stream) {
  const float* x     = (const float*)d_in[0];
  const float* qkv_w = (const float*)d_in[1];
  const float* out_w = (const float*)d_in[2];
  const float* out_b = (const float*)d_in[3];
  const float* dray  = (const float*)d_in[4];
  const int* bfid  = (const int*)d_in[5];
  const int* btid  = (const int*)d_in[6];
  const int* blid  = (const int*)d_in[7];
  const int* bsid  = (const int*)d_in[8];
  const int* nfid  = (const int*)d_in[9];
  const int* ntid  = (const int*)d_in[10];
  const int* nlid  = (const int*)d_in[11];
  const int* nsid  = (const int*)d_in[12];
  const int* nmask = (const int*)d_in[13];

  char* ws = (char*)d_ws;
  short* xb    = (short*)(ws);                  // 12288*1024 bf16 = 25165824 B
  short* qwT   = (short*)(ws + 25165824);       // 3072*1024  bf16 =  6291456 B
  short* owT   = (short*)(ws + 31457280);       // 1024*1024  bf16 =  2097152 B
  float* qbuf  = (float*)(ws + 33554432);       // 1536*1024  f32  =  6291456 B
  short* kvbuf = (short*)(ws + 39845888);       // 12288*2048 bf16 = 50331648 B
  short* obuf  = (short*)(ws + 90177536);       // 1536*1024  bf16 =  3145728 B

  hipMemsetAsync(d_out, 0, (size_t)out_size * sizeof(float), stream);

  conv_bf16<<<6144, 256, 0, stream>>>(x, xb);
  transpose_conv<<<dim3(96, 32), 256, 0, stream>>>(qkv_w, qwT, 1024, 3072);
  transpose_conv<<<dim3(32, 32), 256, 0, stream>>>(out_w, owT, 1024, 1024);

  // Q projection: 1536 x 1024 x 1024
  mfma_gemm<0><<<dim3(8, 12), 256, 0, stream>>>(xb, qwT, qbuf, bfid, btid, nullptr);
  // KV projection: 12288 x 2048 x 1024
  mfma_gemm<1><<<dim3(16, 96), 256, 0, stream>>>(xb, qwT, kvbuf, nfid, ntid, nullptr);
  // fused rotations + attention
  attn_kernel<<<6144, 256, 0, stream>>>(dray, bfid, blid, bsid,
                                        nfid, ntid, nlid, nsid, nmask,
                                        qbuf, (const __hip_bfloat16*)kvbuf,
                                        (__hip_bfloat16*)obuf);
  // output projection + bias + valid mask + scatter: 1536 x 1024 x 1024
  mfma_gemm<2><<<dim3(8, 12), 256, 0, stream>>>(obuf, owT, d_out, bfid, btid, out_b);
}